// Round 2
// baseline (298.055 us; speedup 1.0000x reference)
//
#include <hip/hip_runtime.h>
#include <hip/hip_bf16.h>

#define BATCH 8
#define NN    2048
#define FIN   512
#define FOUT  32
#define GALPHA 0.2f

typedef float  f32x4  __attribute__((ext_vector_type(4)));
typedef __bf16 bf16x8 __attribute__((ext_vector_type(8)));
typedef unsigned short u16;
typedef u16 u16x8 __attribute__((ext_vector_type(8)));

static __device__ __forceinline__ u16 f2bf(float f) {
    __hip_bfloat16 h = __float2bfloat16(f);
    union { __hip_bfloat16 h; u16 u; } c; c.h = h; return c.u;
}
static __device__ __forceinline__ float bf2f(u16 u) {
    union { u16 u; __hip_bfloat16 h; } c; c.u = u; return __bfloat162float(c.h);
}

// K0: w1[i] = sum_o Wfc[o][i]*a1[o], w2 likewise with a2. 1 block x 512 thr. fp32 in.
__global__ void k_w12(const float* __restrict__ Wfc,
                      const float* __restrict__ Wat,
                      float* __restrict__ w1, float* __restrict__ w2) {
    int i = threadIdx.x;            // 0..511
    float s1 = 0.f, s2 = 0.f;
    #pragma unroll
    for (int o = 0; o < FOUT; o++) {
        float wv = Wfc[o * FIN + i];
        s1 += wv * Wat[o];
        s2 += wv * Wat[FOUT + o];
    }
    w1[i] = s1; w2[i] = s2;
}

// K1: f1[r] = x[r,:].w1, f2[r] = x[r,:].w2. Wave per row. grid 4096 x 256. fp32 x.
__global__ void k_f12(const float* __restrict__ x,
                      const float* __restrict__ w1, const float* __restrict__ w2,
                      float* __restrict__ f1, float* __restrict__ f2) {
    int row  = blockIdx.x * 4 + (threadIdx.x >> 6);   // 0..16383
    int lane = threadIdx.x & 63;
    const f32x4* xv = (const f32x4*)(x + (size_t)row * FIN + lane * 8);
    f32x4 xa = xv[0], xb = xv[1];
    const f32x4* w1v = (const f32x4*)(w1 + lane * 8);
    const f32x4* w2v = (const f32x4*)(w2 + lane * 8);
    f32x4 wa = w1v[0], wb = w1v[1], wc = w2v[0], wd = w2v[1];
    float s1 = 0.f, s2 = 0.f;
    #pragma unroll
    for (int j = 0; j < 4; j++) {
        s1 += xa[j] * wa[j]; s2 += xa[j] * wc[j];
        s1 += xb[j] * wb[j]; s2 += xb[j] * wd[j];
    }
    #pragma unroll
    for (int off = 32; off; off >>= 1) {
        s1 += __shfl_xor(s1, off);
        s2 += __shfl_xor(s2, off);
    }
    if (lane == 0) { f1[row] = s1; f2[row] = s2; }
}

// K2: xt[b][i][m] = bf16(x[b][m][i]). 64x64 tiles via LDS. grid 8*32*8 x 256.
__global__ void k_xt(const float* __restrict__ x,
                     __hip_bfloat16* __restrict__ xt) {
    int bx = blockIdx.x;
    int it = bx & 7, mt = (bx >> 3) & 31, b = bx >> 8;
    int m0 = mt * 64, i0 = it * 64;
    __shared__ u16 tile[64][72];   // 144B row stride: balanced bank groups
    int tt = threadIdx.x;
    int mm = tt >> 3;              // 0..31
    int ic = (tt & 7) * 8;         // 0..56
    const float* xb = x + ((size_t)b * NN + m0) * FIN + i0;
    #pragma unroll
    for (int h = 0; h < 2; h++) {
        int m = mm + h * 32;
        const f32x4* src = (const f32x4*)(xb + (size_t)m * FIN + ic);
        f32x4 v0 = src[0], v1 = src[1];
        u16x8 pk;
        #pragma unroll
        for (int j = 0; j < 4; j++) { pk[j] = f2bf(v0[j]); pk[4 + j] = f2bf(v1[j]); }
        *(u16x8*)&tile[m][ic] = pk;
    }
    __syncthreads();
    __hip_bfloat16* xtb = xt + ((size_t)b * FIN + i0) * NN + m0;
    int mc = (tt & 7) * 8;
    #pragma unroll
    for (int h = 0; h < 2; h++) {
        int ii = (tt >> 3) + h * 32;
        u16x8 v;
        #pragma unroll
        for (int j = 0; j < 8; j++) v[j] = tile[mc + j][ii];
        *(u16x8*)(xtb + (size_t)ii * NN + mc) = v;
    }
}

// K3: fused attn-gen + GEMM + softmax-normalize + ELU. fp32 out.
// grid 256 (b = blk&7 -> XCD affinity, rowtile = blk>>3), 512 threads (8 waves).
// Each block: 64 rows x all 512 cols, k-loop over m in steps of 32; adj read once.
__global__ __launch_bounds__(512, 2) void k_main(
    const int* __restrict__ adj, const __hip_bfloat16* __restrict__ xt,
    const float* __restrict__ f1, const float* __restrict__ f2,
    float* __restrict__ out)
{
    const int bx = blockIdx.x;
    const int b = bx & 7, rt = bx >> 3;
    const int n0 = rt * 64;
    const int tid = threadIdx.x;
    const int lane = tid & 63, wv = tid >> 6;
    const int quad = lane >> 4, l15 = lane & 15;

    __shared__ u16 At[2][64 * 40];   // [row][k] bf16, stride 40 (pad 8)
    __shared__ float rs[64];

    // --- A-generation role: thread -> (row = tid>>3, m-chunk = (tid&7)*4) ---
    const int grow = tid >> 3;
    const int gch  = (tid & 7) * 4;
    const int*   adjp = adj + ((size_t)b * NN + (n0 + grow)) * NN + gch;
    const float* f2p  = f2 + b * NN + gch;
    const float  f1v  = f1[b * NN + n0 + grow];
    float rpart = 0.f;

    // --- MFMA role: wave wv owns cols [wv*64, wv*64+64), 4 row-strips x 4 col-strips ---
    const __hip_bfloat16* xtp = xt + ((size_t)(b * FIN) + wv * 64 + l15) * NN + quad * 8;

    f32x4 acc[4][4];
    #pragma unroll
    for (int s = 0; s < 4; s++)
        #pragma unroll
        for (int c = 0; c < 4; c++)
            acc[s][c] = (f32x4){0.f, 0.f, 0.f, 0.f};

    auto gen = [&](int buf, int4 av, float4 fv) {
        const int*   ai = (const int*)&av;
        const float* fi = (const float*)&fv;
        ushort4 pk;
        u16* pp = (u16*)&pk;
        #pragma unroll
        for (int j = 0; j < 4; j++) {
            float s  = f1v + fi[j];
            float ls = fmaxf(s, GALPHA * s);          // leaky_relu
            float ev = (ai[j] != 0) ? __expf(ls) : 0.f;
            u16 hb = f2bf(ev);
            rpart += bf2f(hb);                        // rowsum from bf16-rounded value
            pp[j] = hb;
        }
        *(ushort4*)&At[buf][grow * 40 + gch] = pk;
    };

    // prologue: gen k=0, prefetch adj/f2 k=1, prefetch B k=0
    int4   adjv = *(const int4*)adjp;
    float4 f2v  = *(const float4*)f2p;
    bf16x8 Bv[4], Bn[4];
    #pragma unroll
    for (int c = 0; c < 4; c++)
        Bv[c] = *(const bf16x8*)(xtp + (size_t)(c * 16) * NN);
    gen(0, adjv, f2v);
    adjv = *(const int4*)(adjp + 32);
    f2v  = *(const float4*)(f2p + 32);
    __syncthreads();

    #pragma unroll 2
    for (int k = 0; k < 64; k++) {
        const int cur = k & 1;
        if (k < 63) {   // issue B prefetch for k+1 (consumed next iter)
            const __hip_bfloat16* xk = xtp + (k + 1) * 32;
            #pragma unroll
            for (int c = 0; c < 4; c++)
                Bn[c] = *(const bf16x8*)(xk + (size_t)(c * 16) * NN);
        }
        #pragma unroll
        for (int s = 0; s < 4; s++) {
            bf16x8 Af = *(const bf16x8*)&At[cur][(s * 16 + l15) * 40 + quad * 8];
            #pragma unroll
            for (int c = 0; c < 4; c++)
                acc[s][c] = __builtin_amdgcn_mfma_f32_16x16x32_bf16(Af, Bv[c], acc[s][c], 0, 0, 0);
        }
        if (k < 63) {
            gen(1 - cur, adjv, f2v);                  // A tile for k+1
            if (k < 62) {                              // prefetch adj/f2 for k+2
                adjv = *(const int4*)(adjp + (size_t)(k + 2) * 32);
                f2v  = *(const float4*)(f2p + (k + 2) * 32);
            }
        }
        // LDS-only barrier: global prefetches stay in flight (no vmcnt drain)
        asm volatile("s_waitcnt lgkmcnt(0)\ns_barrier" ::: "memory");
        #pragma unroll
        for (int c = 0; c < 4; c++) Bv[c] = Bn[c];
    }

    // rowsum: reduce over the 8 m-chunk threads of each row
    #pragma unroll
    for (int off = 1; off < 8; off <<= 1) rpart += __shfl_xor(rpart, off);
    if ((tid & 7) == 0) rs[grow] = 1.0f / rpart;
    __syncthreads();

    // epilogue: normalize, ELU, store fp32
    #pragma unroll
    for (int s = 0; s < 4; s++) {
        #pragma unroll
        for (int r = 0; r < 4; r++) {
            const int row = s * 16 + quad * 4 + r;
            const float inv = rs[row];
            float* op = out + ((size_t)b * NN + (n0 + row)) * FIN + wv * 64 + l15;
            #pragma unroll
            for (int c = 0; c < 4; c++) {
                float v = acc[s][c][r] * inv;
                v = v > 0.f ? v : (__expf(v) - 1.f);   // elu
                op[c * 16] = v;
            }
        }
    }
}

extern "C" void kernel_launch(void* const* d_in, const int* in_sizes, int n_in,
                              void* d_out, int out_size, void* d_ws, size_t ws_size,
                              hipStream_t stream) {
    const float* x   = (const float*)d_in[0];
    const int*   adj = (const int*)d_in[1];
    const float* Wfc = (const float*)d_in[2];
    const float* Wat = (const float*)d_in[3];
    float* out = (float*)d_out;

    float* w1 = (float*)d_ws;                       // 512
    float* w2 = w1 + 512;                           // 512
    float* f1 = w2 + 512;                           // 8*2048
    float* f2 = f1 + BATCH * NN;                    // 8*2048
    __hip_bfloat16* xt = (__hip_bfloat16*)(f2 + BATCH * NN);   // 8*512*2048 bf16 (~16.8 MB)

    hipLaunchKernelGGL(k_w12, dim3(1),    dim3(512), 0, stream, Wfc, Wat, w1, w2);
    hipLaunchKernelGGL(k_f12, dim3(4096), dim3(256), 0, stream, x, w1, w2, f1, f2);
    hipLaunchKernelGGL(k_xt,  dim3(2048), dim3(256), 0, stream, x, xt);
    hipLaunchKernelGGL(k_main, dim3(256), dim3(512), 0, stream, adj, xt, f1, f2, out);
}